// Round 2
// baseline (165.285 us; speedup 1.0000x reference)
//
#include <hip/hip_runtime.h>
#include <hip/hip_cooperative_groups.h>

namespace cg = cooperative_groups;

// ---- problem constants (fixed by reference) ----
#define ROWN   32768
#define NSTEP  25
#define NIN    36
#define NHID   5
#define NOUT   3
#define TTOT   (NSTEP * ROWN)      // 819200 total LIF steps
#define OUTHALF (TTOT * NOUT)      // 2457600 floats per tuple element

// ---- speculation / parallelization parameters ----
#define CHL    64                  // chunk length (bitwise-verified config)
#define WARM   384                 // warmup steps (bitwise-verified)
#define NCH    (TTOT / CHL)        // 12800 chunks
#define GPW    8                   // chunks per wave (8 lanes per chunk)
#define WPB    4                   // waves per block
#define NWAVE  (NCH / GPW)         // 1600 waves
#define NBLK   (NWAVE / WPB)       // 400 blocks of 256 threads (cooperative)
#define MLAG   8                   // m2 pipeline lag == d2 LDS prefetch depth
#define DLAG   16                  // dot global prefetch depth
#define EXT    640                 // duplicated rows appended to dot table
                                   // max overrun row: 32767+16+57*8-1 = 33238 < 33408

// ---- ws layout (float offsets) ----
#define DOTROWS (ROWN + EXT)
#define WS_DOT   0                    // [DOTROWS][8] padded dot products (~1.07 MB)
#define WS_SPECF (DOTROWS * 8)        // [NWAVE][8] wave-FIRST-chunk spec states
#define WS_ENDL  (WS_SPECF + NWAVE*8) // [NWAVE][8] wave-LAST-chunk end states
#define WS_FLAG  (WS_ENDL + NWAVE*8)  // int flag

// ---- 8-lane-per-chunk speculative scan (CHL=64 structure, verified) ----
// lane = g*8 + h.  h<5: m1 comp h (input = dot[t][h], global, 16-deep prefetch).
//                  h>=5: m2 comp h-5 (input = LUT d2, MLAG steps behind m1).
// Unified step: m = (0.9*m + inp) + bias; spike iff m>1; m -= spike.
// spec/end states returned in registers (checked via shuffle by caller).
template<bool GUARD>
__device__ __forceinline__ void run_chunks(
    const char* __restrict__ dotb,      // byte base of dot table
    const char* __restrict__ lutrow,    // this lane's LUT row base (LDS)
    float bias, int c, int h, bool isM2, int gsh,
    char* __restrict__ outb, char* __restrict__ out2b,
    float& mspec, float& mend)
{
#pragma clang fp contract(off)
    const int ts = c * CHL;
    const int t0 = ts - WARM;                     // <0 only in GUARD block
    float m = 0.0f;
    float dvbuf[DLAG], d2buf[MLAG], sbuf[8];
    const int dco = (isM2 ? 4 : h) << 2;          // dot col byte off (m2: dummy, coalesced)
    unsigned offb = ((unsigned)(t0 & (ROWN - 1)) << 5) + (unsigned)dco;
#pragma unroll
    for (int k = 0; k < DLAG; ++k)                // prime the 16-deep dot pipeline
        dvbuf[k] = *(const float*)(dotb + offb + k * 32);
    offb += DLAG * 32;
#pragma unroll
    for (int k = 0; k < MLAG; ++k) d2buf[k] = 0.0f;
    int tg = t0 - (isM2 ? MLAG : 0);              // logical clock (GUARD only)
    unsigned obb = (unsigned)ts * 12u + (unsigned)((isM2 ? (h - NHID) : 0) << 2);

// One 8-step block. HALF selects the dvbuf half (16-step rotation).
#define BLK8(HALF, STORE)                                                    \
  {                                                                          \
    _Pragma("unroll")                                                        \
    for (int k = 0; k < 8; ++k) {                                            \
        float inp = isM2 ? d2buf[k] : dvbuf[(HALF) + k];                     \
        float u = 0.9f * m;                                                  \
        u = u + inp;                                                         \
        u = u + bias;                                                        \
        bool sp = u > 1.0f;                                                  \
        unsigned long long bal = __ballot(sp);                               \
        float um1 = u - 1.0f;                                                \
        m = sp ? um1 : u;                                                    \
        if (GUARD) { if (tg < 0) m = 0.0f; ++tg; }                           \
        dvbuf[(HALF) + k] = *(const float*)(dotb + offb + k * 32);           \
        unsigned a = (unsigned)((bal << 2) >> gsh) & 124u;                   \
        d2buf[k] = *(const float*)(lutrow + a);                              \
        if (STORE) sbuf[k] = sp ? 1.0f : 0.0f;                               \
    }                                                                        \
    offb += 256u;                                                            \
    if (STORE) {                                                             \
        if (isM2) {                                                          \
            _Pragma("unroll")                                                \
            for (int k = 0; k < 8; ++k) {                                    \
                *(float*)(outb  + obb + k * 12) = sbuf[k];                   \
                *(float*)(out2b + obb + k * 12) = sbuf[k];                   \
            }                                                                \
        }                                                                    \
        obb += 96u;                                                          \
    }                                                                        \
  }

    // warmup: 48 blocks = 384 steps (halves alternate 0,8)
    for (int n = 0; n < 24; ++n) { BLK8(0, false) BLK8(8, false) }
    if (!isM2) mspec = m;                // m1 state at t = ts
    BLK8(0, false)                        // m2 finishes warmup
    if (isM2) mspec = m;                 // m2 state at t = ts
    // store region: 8 blocks = 64 m2-steps (halves 8,0,8,0,8,0,8,0)
    for (int n = 0; n < 3; ++n) { BLK8(8, true) BLK8(0, true) }
    BLK8(8, true)
    if (!isM2) mend = m;                 // m1 state at t = ts+CHL
    BLK8(0, true)
    if (isM2) mend = m;                  // m2 state at t = ts+CHL
#undef BLK8
}

// ---- exact scalar step (fallback path only) ----
template<bool STORE>
__device__ __forceinline__ void lif_step(int t, const float* __restrict__ dot,
                                         float m1[NHID], float m2[NOUT],
                                         const float B1[NHID],
                                         const float W2[NOUT][NHID],
                                         const float B2[NOUT],
                                         float* __restrict__ out) {
#pragma clang fp contract(off)
    int r = t & (ROWN - 1);
    const float4 lo = *reinterpret_cast<const float4*>(dot + r * 8);
    const float d4 = dot[r * 8 + 4];
    float dv[NHID] = { lo.x, lo.y, lo.z, lo.w, d4 };
    float s1f[NHID];
#pragma unroll
    for (int h = 0; h < NHID; ++h) {
        float u = 0.9f * m1[h];
        u = u + dv[h];
        u = u + B1[h];
        float s = (u > 1.0f) ? 1.0f : 0.0f;
        m1[h] = u - s;
        s1f[h] = s;
    }
#pragma unroll
    for (int o = 0; o < NOUT; ++o) {
        float d2 = W2[o][0] * s1f[0];
        d2 = d2 + W2[o][1] * s1f[1];
        d2 = d2 + W2[o][2] * s1f[2];
        d2 = d2 + W2[o][3] * s1f[3];
        d2 = d2 + W2[o][4] * s1f[4];
        float u = 0.9f * m2[o];
        u = u + d2;
        u = u + B2[o];
        float s = (u > 1.0f) ? 1.0f : 0.0f;
        m2[o] = u - s;
        if (STORE) {
            out[t * NOUT + o] = s;
            out[OUTHALF + t * NOUT + o] = s;
        }
    }
}

// ============ single cooperative kernel: dots -> chunks(+check) -> verify/fallback ============
__global__ void __launch_bounds__(256, 2)
snn_fused(const float* __restrict__ data, const float* __restrict__ w1,
          const float* __restrict__ b1g, const float* __restrict__ w2g,
          const float* __restrict__ b2g, float* __restrict__ out,
          float* __restrict__ ws)
{
    __shared__ float lutT[3 * 32];       // transposed LUT: lutT[o][mask], 4B stride
    const int tid = threadIdx.x;

    // ---- LUT (exact: lutT[o*32+mask] = w2[o] @ bits(mask)) ----
    if (tid < 32) {
#pragma clang fp contract(off)
        float b0 = (float)(tid & 1), b1v = (float)((tid >> 1) & 1),
              b2v = (float)((tid >> 2) & 1), b3v = (float)((tid >> 3) & 1),
              b4v = (float)((tid >> 4) & 1);
#pragma unroll
        for (int o = 0; o < NOUT; ++o) {
            float d = w2g[o * NHID + 0] * b0;
            d = d + w2g[o * NHID + 1] * b1v;
            d = d + w2g[o * NHID + 2] * b2v;
            d = d + w2g[o * NHID + 3] * b3v;
            d = d + w2g[o * NHID + 4] * b4v;
            lutT[o * 32 + tid] = d;
        }
    }

    // ---- phase 1: dot table (exact sequential-j order, contract off) ----
    {
        int r = blockIdx.x * 256 + tid;
        if (r == 0) ((int*)ws)[WS_FLAG] = 0;
        if (r < ROWN) {
#pragma clang fp contract(off)
            const float4* x4 = reinterpret_cast<const float4*>(data + r * NIN);
            float4 xv[9];
#pragma unroll
            for (int q = 0; q < 9; ++q) xv[q] = x4[q];
            const float* xs = reinterpret_cast<const float*>(xv);
            float acc[NHID] = {0.f, 0.f, 0.f, 0.f, 0.f};
#pragma unroll
            for (int j = 0; j < NIN; ++j) {
                float x = xs[j];
#pragma unroll
                for (int hh = 0; hh < NHID; ++hh) {
                    float p = w1[hh * NIN + j] * x;
                    acc[hh] = acc[hh] + p;
                }
            }
            float* d = ws + WS_DOT + r * 8;
#pragma unroll
            for (int hh = 0; hh < NHID; ++hh) d[hh] = acc[hh];
            d[5] = 0.f; d[6] = 0.f; d[7] = 0.f;
            if (r < EXT) {
                float* d2 = ws + WS_DOT + (ROWN + r) * 8;
#pragma unroll
                for (int hh = 0; hh < NHID; ++hh) d2[hh] = acc[hh];
                d2[5] = 0.f; d2[6] = 0.f; d2[7] = 0.f;
            }
        }
    }

    cg::this_grid().sync();   // dot table + flag=0 visible to all

    // ---- phase 2: speculative chunk scan ----
    {
        int lane = tid & 63;
        int wid  = tid >> 6;
        int gwid = blockIdx.x * WPB + wid;            // 0..1599
        int g = lane >> 3, h = lane & 7;
        bool isM2 = (h >= NHID);
        float bias = isM2 ? b2g[h - NHID] : b1g[h];
        int c = gwid * GPW + g;
        int gsh = g << 3;
        const char* lutrow = (const char*)lutT + (isM2 ? ((h - NHID) << 7) : 0);
        const char* dotb = (const char*)(ws + WS_DOT);
        char* outb  = (char*)out;
        char* out2b = (char*)(out + OUTHALF);
        float mspec, mend;
        // only chunks with ts < WARM (c<6, all in wave 0) need GUARD
        if (gwid == 0)
            run_chunks<true >(dotb, lutrow, bias, c, h, isM2, gsh, outb, out2b, mspec, mend);
        else
            run_chunks<false>(dotb, lutrow, bias, c, h, isM2, gsh, outb, out2b, mspec, mend);

        // in-wave chain check: chunk c vs c-1 (8 lanes away), 7/8 of all pairs
        int src = (lane >= 8) ? (lane - 8) : lane;
        float prevend = __shfl(mend, src);
        bool bad = (g > 0) && (prevend != mspec);
        if (__any(bad) && lane == 0) atomicOr((int*)ws + WS_FLAG, 1);

        // wave-boundary states for cross-wave check
        float* specF = ws + WS_SPECF;
        float* endL  = ws + WS_ENDL;
        if (g == 0) specF[gwid * 8 + h] = mspec;
        if (g == 7) endL [gwid * 8 + h] = mend;
    }

    cg::this_grid().sync();   // flag + boundary states visible

    // ---- phase 3: boundary check + (never-taken) exact fallback, block 0 only ----
    if (blockIdx.x == 0) {
        __shared__ int sflag;
        if (tid == 0) sflag = 0;
        __syncthreads();
        const float* specF = ws + WS_SPECF;
        const float* endL  = ws + WS_ENDL;
        for (int w = 1 + tid; w < NWAVE; w += 256) {
            bool bad = false;
#pragma unroll
            for (int i = 0; i < 8; ++i)
                bad = bad || (specF[w * 8 + i] != endL[(w - 1) * 8 + i]);
            if (bad) atomicOr(&sflag, 1);
        }
        __syncthreads();
        if (tid == 0) {
            int* flag = (int*)ws + WS_FLAG;
            int f = atomicOr(flag, sflag);            // merge + read phase-2 flags
            if ((f | sflag) != 0) {                   // exact sequential fallback
                float B1[NHID], W2[NOUT][NHID], B2[NOUT];
#pragma unroll
                for (int h = 0; h < NHID; ++h) B1[h] = b1g[h];
#pragma unroll
                for (int o = 0; o < NOUT; ++o) {
                    B2[o] = b2g[o];
#pragma unroll
                    for (int h = 0; h < NHID; ++h) W2[o][h] = w2g[o * NHID + h];
                }
                float m1[NHID] = {0,0,0,0,0};
                float m2[NOUT] = {0,0,0};
                for (int t = 0; t < TTOT; ++t)
                    lif_step<true>(t, ws + WS_DOT, m1, m2, B1, W2, B2, out);
            }
        }
    }
}

extern "C" void kernel_launch(void* const* d_in, const int* in_sizes, int n_in,
                              void* d_out, int out_size, void* d_ws, size_t ws_size,
                              hipStream_t stream) {
    const float* data = (const float*)d_in[0];
    const float* w1   = (const float*)d_in[1];
    const float* b1   = (const float*)d_in[2];
    const float* w2   = (const float*)d_in[3];
    const float* b2   = (const float*)d_in[4];
    float* out = (float*)d_out;
    float* ws  = (float*)d_ws;

    void* args[] = { (void*)&data, (void*)&w1, (void*)&b1, (void*)&w2,
                     (void*)&b2,   (void*)&out, (void*)&ws };
    hipLaunchCooperativeKernel((const void*)snn_fused, dim3(NBLK), dim3(256),
                               args, 0, stream);
}

// Round 3
// 49.639 us; speedup vs baseline: 3.3298x; 3.3298x over previous
//
#include <hip/hip_runtime.h>

// ---- problem constants (fixed by reference) ----
#define ROWN   32768
#define NSTEP  25
#define NIN    36
#define NHID   5
#define NOUT   3
#define TTOT   (NSTEP * ROWN)      // 819200 total LIF steps
#define OUTHALF (TTOT * NOUT)      // 2457600 floats per tuple element

// ---- speculation / parallelization parameters (round-0 verified geometry) ----
#define CHL    64                  // chunk length (bitwise-verified)
#define WARM   384                 // warmup steps (bitwise-verified)
#define NCH    (TTOT / CHL)        // 12800 chunks
#define GPW    8                   // chunks per wave (8 lanes per chunk)
#define NWAVE  (NCH / GPW)         // 1600 waves = 1600 workgroups of 64
#define MLAG   8                   // m2 pipeline lag == d2 LDS prefetch depth
#define DLAG   16                  // dot global prefetch depth
#define EXT    640                 // duplicated rows appended to dot table
                                   // max row touched: 32767 + 456 + 16 = 33239 < 33408

// ---- ws layout (float offsets) ----
#define DOTROWS (ROWN + EXT)
#define WS_DOT   0                    // [DOTROWS][8] padded dot products (~1.07 MB)
#define WS_SPECF (DOTROWS * 8)        // [NWAVE][8] wave-FIRST-chunk spec states
#define WS_ENDL  (WS_SPECF + NWAVE*8) // [NWAVE][8] wave-LAST-chunk end states
#define WS_FLAG  (WS_ENDL + NWAVE*8)  // int flag

// Precompute dot1[r][h] = sum_j w1[h][j]*data[r][j], exact sequential-j order,
// contract off (bitwise-matches reference). Rows 0..EXT-1 duplicated at ROWN+r
// so the scan loop needs no wrap mask.
__global__ void snn_dots(const float* __restrict__ data,
                         const float* __restrict__ w1,
                         float* __restrict__ ws) {
#pragma clang fp contract(off)
    int r = blockIdx.x * blockDim.x + threadIdx.x;
    if (r == 0) ((int*)(ws))[WS_FLAG] = 0;
    if (r >= ROWN) return;
    const float4* x4 = reinterpret_cast<const float4*>(data + r * NIN);
    float4 xv[9];
#pragma unroll
    for (int q = 0; q < 9; ++q) xv[q] = x4[q];
    const float* xs = reinterpret_cast<const float*>(xv);
    float acc[NHID] = {0.f, 0.f, 0.f, 0.f, 0.f};
#pragma unroll
    for (int j = 0; j < NIN; ++j) {
        float x = xs[j];
#pragma unroll
        for (int h = 0; h < NHID; ++h) {
            float p = w1[h * NIN + j] * x;
            acc[h] = acc[h] + p;
        }
    }
    float* d = ws + WS_DOT + r * 8;
#pragma unroll
    for (int h = 0; h < NHID; ++h) d[h] = acc[h];
    d[5] = 0.f; d[6] = 0.f; d[7] = 0.f;
    if (r < EXT) {
        float* d2 = ws + WS_DOT + (ROWN + r) * 8;
#pragma unroll
        for (int h = 0; h < NHID; ++h) d2[h] = acc[h];
        d2[5] = 0.f; d2[6] = 0.f; d2[7] = 0.f;
    }
}

// ---- 8-lane-per-chunk speculative scan ----
// lane = g*8 + h.  h<5: m1 comp h (input = dot[t][h], global, 16-deep prefetch).
//                  h>=5: m2 comp h-5 (input = LUT d2, MLAG steps behind m1).
// Unified step: m = (0.9*m + inp) + bias; spike iff m>1; m -= spike.
// spec/end states returned in registers (checked via shuffle by caller).
template<bool GUARD>
__device__ __forceinline__ void run_chunks(
    const char* __restrict__ dotb,      // byte base of dot table
    const char* __restrict__ lutrow,    // this lane's LUT row base (LDS, 33-float stride)
    float bias, int c, int h, bool isM2, int gsh,
    char* __restrict__ outb, char* __restrict__ out2b,
    float& mspec, float& mend)
{
#pragma clang fp contract(off)
    const int ts = c * CHL;
    const int t0 = ts - WARM;                     // <0 only in GUARD block
    float m = 0.0f;
    float dvbuf[DLAG], d2buf[MLAG], sbuf[8];
    const int dco = (isM2 ? 4 : h) << 2;          // dot col byte off (m2: dummy, coalesced)
    unsigned offb = ((unsigned)(t0 & (ROWN - 1)) << 5) + (unsigned)dco;
#pragma unroll
    for (int k = 0; k < DLAG; ++k)                // prime the 16-deep dot pipeline
        dvbuf[k] = *(const float*)(dotb + offb + k * 32);
    offb += DLAG * 32;
#pragma unroll
    for (int k = 0; k < MLAG; ++k) d2buf[k] = 0.0f;
    int tg = t0 - (isM2 ? MLAG : 0);              // logical clock (GUARD only)
    unsigned obb = (unsigned)ts * 12u + (unsigned)((isM2 ? (h - NHID) : 0) << 2);

// One 8-step block. HALF selects the dvbuf half (16-step rotation).
#define BLK8(HALF, STORE)                                                    \
  {                                                                          \
    _Pragma("unroll")                                                        \
    for (int k = 0; k < 8; ++k) {                                            \
        float inp = isM2 ? d2buf[k] : dvbuf[(HALF) + k];                     \
        float u = 0.9f * m;                                                  \
        u = u + inp;                                                         \
        u = u + bias;                                                        \
        bool sp = u > 1.0f;                                                  \
        unsigned long long bal = __ballot(sp);                               \
        float um1 = u - 1.0f;                                                \
        m = sp ? um1 : u;                                                    \
        if (GUARD) { if (tg < 0) m = 0.0f; ++tg; }                           \
        dvbuf[(HALF) + k] = *(const float*)(dotb + offb + k * 32);           \
        unsigned a = (unsigned)((bal << 2) >> gsh) & 124u;                   \
        d2buf[k] = *(const float*)(lutrow + a);                              \
        if (STORE) sbuf[k] = sp ? 1.0f : 0.0f;                               \
    }                                                                        \
    offb += 256u;                                                            \
    if (STORE) {                                                             \
        if (isM2) {                                                          \
            _Pragma("unroll")                                                \
            for (int k = 0; k < 8; ++k) {                                    \
                *(float*)(outb  + obb + k * 12) = sbuf[k];                   \
                *(float*)(out2b + obb + k * 12) = sbuf[k];                   \
            }                                                                \
        }                                                                    \
        obb += 96u;                                                          \
    }                                                                        \
  }

    // warmup: 48 blocks = 384 steps (halves alternate 0,8)
    for (int n = 0; n < 24; ++n) { BLK8(0, false) BLK8(8, false) }
    if (!isM2) mspec = m;                // m1 state at t = ts
    BLK8(0, false)                        // m2 finishes warmup
    if (isM2) mspec = m;                 // m2 state at t = ts
    // store region: 8 blocks = 64 m2-steps (halves 8,0,8,0,8,0,8,0)
    for (int n = 0; n < 3; ++n) { BLK8(8, true) BLK8(0, true) }
    BLK8(8, true)
    if (!isM2) mend = m;                 // m1 state at t = ts+CHL
    BLK8(0, true)
    if (isM2) mend = m;                  // m2 state at t = ts+CHL
#undef BLK8
}

// waves_per_eu(1,2): only ~1.56 waves/SIMD exist grid-wide, so capping the
// occupancy target at 2 costs nothing and frees the allocator to keep the
// 16-deep dv / 8-deep d2 pipelines register-resident (round-0 VGPR_Count=24
// proves they were collapsed/spilled under the default max-occupancy target).
__global__ void __attribute__((amdgpu_flat_work_group_size(64, 64),
                               amdgpu_waves_per_eu(1, 2)))
snn_chunks(const float* __restrict__ ws,
           const float* __restrict__ b1g, const float* __restrict__ w2g,
           const float* __restrict__ b2g,
           float* __restrict__ out, float* __restrict__ specF,
           float* __restrict__ endL) {
    __shared__ float lutT[3 * 33];       // padded LUT: lutT[o*33+mask], banks o+mask
    int lane = threadIdx.x;
    if (lane < 32) {                      // exact: lutT[o*33+mask] = w2[o]@bits(mask)
#pragma clang fp contract(off)
        float b0 = (float)(lane & 1), b1v = (float)((lane >> 1) & 1),
              b2v = (float)((lane >> 2) & 1), b3v = (float)((lane >> 3) & 1),
              b4v = (float)((lane >> 4) & 1);
#pragma unroll
        for (int o = 0; o < NOUT; ++o) {
            float d = w2g[o * NHID + 0] * b0;
            d = d + w2g[o * NHID + 1] * b1v;
            d = d + w2g[o * NHID + 2] * b2v;
            d = d + w2g[o * NHID + 3] * b3v;
            d = d + w2g[o * NHID + 4] * b4v;
            lutT[o * 33 + lane] = d;
        }
    }
    __syncthreads();
    int gwid = blockIdx.x;                         // 0..1599
    int g = lane >> 3, h = lane & 7;
    bool isM2 = (h >= NHID);
    float bias = isM2 ? b2g[h - NHID] : b1g[h];
    int c = gwid * GPW + g;
    int gsh = g << 3;                              // ballot >> (group*8)
    const char* lutrow = (const char*)lutT + (isM2 ? ((h - NHID) * 132) : 0);
    const char* dotb = (const char*)(ws + WS_DOT);
    char* outb  = (char*)out;
    char* out2b = (char*)(out + OUTHALF);
    float mspec, mend;
    // only chunks with ts < WARM (c<6, all in wave 0) need GUARD
    if (gwid == 0)
        run_chunks<true >(dotb, lutrow, bias, c, h, isM2, gsh, outb, out2b, mspec, mend);
    else
        run_chunks<false>(dotb, lutrow, bias, c, h, isM2, gsh, outb, out2b, mspec, mend);

    // in-wave chain check: chunk c vs c-1 (8 lanes away), 7/8 of all pairs
    int src = (lane >= 8) ? (lane - 8) : lane;
    float prevend = __shfl(mend, src);
    bool bad = (g > 0) && (prevend != mspec);
    int* flag = (int*)(ws + WS_FLAG);
    if (__any(bad) && lane == 0) atomicOr(flag, 1);

    // wave-boundary states for cross-wave check
    if (g == 0) specF[gwid * 8 + h] = mspec;
    if (g == 7) endL [gwid * 8 + h] = mend;
}

// ---- exact scalar step (fallback path only) ----
template<bool STORE>
__device__ __forceinline__ void lif_step(int t, const float* __restrict__ dot,
                                         float m1[NHID], float m2[NOUT],
                                         const float B1[NHID],
                                         const float W2[NOUT][NHID],
                                         const float B2[NOUT],
                                         float* __restrict__ out) {
#pragma clang fp contract(off)
    int r = t & (ROWN - 1);
    const float4 lo = *reinterpret_cast<const float4*>(dot + r * 8);
    const float d4 = dot[r * 8 + 4];
    float dv[NHID] = { lo.x, lo.y, lo.z, lo.w, d4 };
    float s1f[NHID];
#pragma unroll
    for (int h = 0; h < NHID; ++h) {
        float u = 0.9f * m1[h];
        u = u + dv[h];
        u = u + B1[h];
        float s = (u > 1.0f) ? 1.0f : 0.0f;
        m1[h] = u - s;
        s1f[h] = s;
    }
#pragma unroll
    for (int o = 0; o < NOUT; ++o) {
        float d2 = W2[o][0] * s1f[0];
        d2 = d2 + W2[o][1] * s1f[1];
        d2 = d2 + W2[o][2] * s1f[2];
        d2 = d2 + W2[o][3] * s1f[3];
        d2 = d2 + W2[o][4] * s1f[4];
        float u = 0.9f * m2[o];
        u = u + d2;
        u = u + B2[o];
        float s = (u > 1.0f) ? 1.0f : 0.0f;
        m2[o] = u - s;
        if (STORE) {
            out[t * NOUT + o] = s;
            out[OUTHALF + t * NOUT + o] = s;
        }
    }
}

// Merged boundary-check + (never-taken) exact fallback. Single block.
// Wave-boundary pairs: spec_first[w] must equal end_last[w-1] bitwise.
// All-equal + in-wave checks + exact chunk 0 => outputs exact by induction.
__global__ void snn_verify(const float* __restrict__ ws_base,
                           const float* __restrict__ specF,
                           const float* __restrict__ endL,
                           const float* __restrict__ b1g,
                           const float* __restrict__ w2g,
                           const float* __restrict__ b2g,
                           float* __restrict__ out) {
    __shared__ int sflag;
    int tid = threadIdx.x;
    if (tid == 0) sflag = 0;
    __syncthreads();
    for (int w = 1 + tid; w < NWAVE; w += 256) {
        bool bad = false;
#pragma unroll
        for (int i = 0; i < 8; ++i)
            bad = bad || (specF[w * 8 + i] != endL[(w - 1) * 8 + i]);
        if (bad) atomicOr(&sflag, 1);
    }
    __syncthreads();
    if (tid == 0) {
        int* flag = (int*)(ws_base + WS_FLAG);
        int f = *flag | sflag;
        if (f != 0) {                       // exact sequential fallback
            float B1[NHID], W2[NOUT][NHID], B2[NOUT];
#pragma unroll
            for (int h = 0; h < NHID; ++h) B1[h] = b1g[h];
#pragma unroll
            for (int o = 0; o < NOUT; ++o) {
                B2[o] = b2g[o];
#pragma unroll
                for (int h = 0; h < NHID; ++h) W2[o][h] = w2g[o * NHID + h];
            }
            float m1[NHID] = {0,0,0,0,0};
            float m2[NOUT] = {0,0,0};
            for (int t = 0; t < TTOT; ++t)
                lif_step<true>(t, ws_base + WS_DOT, m1, m2, B1, W2, B2, out);
        }
    }
}

extern "C" void kernel_launch(void* const* d_in, const int* in_sizes, int n_in,
                              void* d_out, int out_size, void* d_ws, size_t ws_size,
                              hipStream_t stream) {
    const float* data = (const float*)d_in[0];
    const float* w1   = (const float*)d_in[1];
    const float* b1   = (const float*)d_in[2];
    const float* w2   = (const float*)d_in[3];
    const float* b2   = (const float*)d_in[4];
    float* out = (float*)d_out;
    float* ws  = (float*)d_ws;
    float* specF = ws + WS_SPECF;
    float* endL  = ws + WS_ENDL;

    hipLaunchKernelGGL(snn_dots,   dim3(ROWN / 256), dim3(256), 0, stream, data, w1, ws);
    hipLaunchKernelGGL(snn_chunks, dim3(NWAVE),      dim3(64),  0, stream,
                       ws, b1, w2, b2, out, specF, endL);
    hipLaunchKernelGGL(snn_verify, dim3(1),          dim3(256), 0, stream,
                       ws, specF, endL, b1, w2, b2, out);
}

// Round 4
// 41.097 us; speedup vs baseline: 4.0219x; 1.2079x over previous
//
#include <hip/hip_runtime.h>

// ---- problem constants (fixed by reference) ----
#define ROWN   32768
#define NSTEP  25
#define NIN    36
#define NHID   5
#define NOUT   3
#define TTOT   (NSTEP * ROWN)      // 819200 total LIF steps
#define OUTHALF (TTOT * NOUT)      // 2457600 floats per tuple element

// ---- speculation / parallelization parameters ----
#define CHL    64                  // chunk length (steps) -> 1600 waves
#define WARM   384                 // warmup steps (bitwise-verified)
#define NCH    (TTOT / CHL)        // 12800 chunks
#define GPW    8                   // chunks per wave (8 lanes per chunk)
#define MLAG   8                   // m2 pipeline lag == d2 LDS prefetch depth
#define DLAG   16                  // dot global prefetch depth (~380cy coverage)
#define NBLK   (NCH / GPW)         // 1600 blocks of 64 threads
#define EXT    640                 // duplicated rows appended to dot table
                                   // max row touched: 32767 + 471 = 33238 < 33408

// ---- ws layout (float offsets) ----
#define DOTROWS (ROWN + EXT)
#define WS_DOT  0                  // [DOTROWS][8] padded dot products (~1.07 MB)
#define WS_SPEC (DOTROWS * 8)      // [NCH][8] speculative post-warmup states
#define WS_END  (WS_SPEC + NCH*8)  // [NCH][8] chunk end states
#define WS_FLAG (WS_END + NCH*8)   // int flag

// Precompute dot1[r][h] = sum_j w1[h][j]*data[r][j], exact sequential-j order,
// contract off (matches reference fp trajectory bitwise). Rows 0..EXT-1 are
// duplicated at ROWN+r so the scan loop needs no wrap mask.
__global__ void snn_dots(const float* __restrict__ data,
                         const float* __restrict__ w1,
                         float* __restrict__ ws) {
#pragma clang fp contract(off)
    int r = blockIdx.x * blockDim.x + threadIdx.x;
    if (r == 0) ((int*)ws)[WS_FLAG] = 0;
    if (r >= ROWN) return;
    const float4* x4 = reinterpret_cast<const float4*>(data + r * NIN);
    float4 xv[9];
#pragma unroll
    for (int q = 0; q < 9; ++q) xv[q] = x4[q];
    const float* xs = reinterpret_cast<const float*>(xv);
    float acc[NHID] = {0.f, 0.f, 0.f, 0.f, 0.f};
#pragma unroll
    for (int j = 0; j < NIN; ++j) {
        float x = xs[j];
#pragma unroll
        for (int h = 0; h < NHID; ++h) {
            float p = w1[h * NIN + j] * x;
            acc[h] = acc[h] + p;
        }
    }
    float* d = ws + WS_DOT + r * 8;
#pragma unroll
    for (int h = 0; h < NHID; ++h) d[h] = acc[h];
    d[5] = 0.f; d[6] = 0.f; d[7] = 0.f;
    if (r < EXT) {
        float* d2 = ws + WS_DOT + (ROWN + r) * 8;
#pragma unroll
        for (int h = 0; h < NHID; ++h) d2[h] = acc[h];
        d2[5] = 0.f; d2[6] = 0.f; d2[7] = 0.f;
    }
}

// ---- 8-lane-per-chunk speculative scan ----
// lane = g*8 + h.  h<5: m1 comp h (input = dot[t][h], global, deep prefetch).
//                  h>=5: m2 comp h-5 (input = LUT d2, MLAG steps behind m1).
// Unified step: m = (0.9*m + inp) + bias; spike iff m>1; m -= spike.
// NEW vs round 0: the 8 dot-table loads are CLUSTERED at block end and pinned
// with sched_barrier(0) so the scheduler cannot sink them toward their uses
// (round-0 VGPR_Count=24 proved it collapsed the 16-deep pipeline to ~1,
// exposing ~200cy L2 latency per step). Arithmetic sequence is unchanged.
template<bool GUARD>
__device__ __forceinline__ void run_chunks(
    const char* __restrict__ dotb,      // byte base of dot table
    const char* __restrict__ lutrow,    // this lane's LUT row base (LDS, stride 33)
    float bias, int c, int h, bool isM2, int gsh,
    char* __restrict__ outb, char* __restrict__ out2b,
    float* __restrict__ spec, float* __restrict__ endst)
{
#pragma clang fp contract(off)
    const int ts = c * CHL;
    const int t0 = ts - WARM;                     // <0 only in GUARD block
    float m = 0.0f;
    float dvbuf[DLAG], d2buf[MLAG], sbuf[8];
    const int dco = (isM2 ? 4 : h) << 2;          // dot col byte off (m2: dummy, coalesced)
    unsigned offb = ((unsigned)(t0 & (ROWN - 1)) << 5) + (unsigned)dco;
#pragma unroll
    for (int k = 0; k < DLAG; ++k)                // prime the 16-deep dot pipeline
        dvbuf[k] = *(const float*)(dotb + offb + k * 32);
    offb += DLAG * 32;
#pragma unroll
    for (int k = 0; k < MLAG; ++k) d2buf[k] = 0.0f;
    int tg = t0 - (isM2 ? MLAG : 0);              // logical clock (GUARD only)
    unsigned obb = (unsigned)ts * 12u + (unsigned)((isM2 ? (h - NHID) : 0) << 2);

// One 8-step block. HALF selects the dvbuf half (16-step rotation).
// Phase 1: 8 compute steps (d2 LDS reads stay in-slot -> 8-step spacing).
// Phase 2: 8 clustered dot loads (slot HALF+k consumed again at step k of the
//          next-next block, >=8 steps away >= ~224cy > L2 latency).
// Phase 3: stores (STORE blocks), then sched_barrier(0) pins everything.
#define BLK8(HALF, STORE)                                                    \
  {                                                                          \
    _Pragma("unroll")                                                        \
    for (int k = 0; k < 8; ++k) {                                            \
        float inp = isM2 ? d2buf[k] : dvbuf[(HALF) + k];                     \
        float u = 0.9f * m;                                                  \
        u = u + inp;                                                         \
        u = u + bias;                                                        \
        bool sp = u > 1.0f;                                                  \
        unsigned long long bal = __ballot(sp);                               \
        float um1 = u - 1.0f;                                                \
        m = sp ? um1 : u;                                                    \
        if (GUARD) { if (tg < 0) m = 0.0f; ++tg; }                           \
        unsigned a = (unsigned)((bal << 2) >> gsh) & 124u;                   \
        d2buf[k] = *(const float*)(lutrow + a);                              \
        if (STORE) sbuf[k] = sp ? 1.0f : 0.0f;                               \
    }                                                                        \
    _Pragma("unroll")                                                        \
    for (int k = 0; k < 8; ++k)                                              \
        dvbuf[(HALF) + k] = *(const float*)(dotb + offb + k * 32);           \
    offb += 256u;                                                            \
    if (STORE) {                                                             \
        if (isM2) {                                                          \
            _Pragma("unroll")                                                \
            for (int k = 0; k < 8; ++k) {                                    \
                *(float*)(outb  + obb + k * 12) = sbuf[k];                   \
                *(float*)(out2b + obb + k * 12) = sbuf[k];                   \
            }                                                                \
        }                                                                    \
        obb += 96u;                                                          \
    }                                                                        \
    __builtin_amdgcn_sched_barrier(0);                                       \
  }

    // warmup: 48 blocks = 384 steps (halves alternate 0,8)
    for (int n = 0; n < 24; ++n) { BLK8(0, false) BLK8(8, false) }
    if (!isM2) spec[c * 8 + h] = m;      // m1 state at t = ts
    BLK8(0, false)                        // m2 finishes warmup
    if (isM2) spec[c * 8 + h] = m;       // m2 state at t = ts
    // store region: 8 blocks = 64 m2-steps (halves 8,0,8,0,8,0,8,0)
    for (int n = 0; n < 3; ++n) { BLK8(8, true) BLK8(0, true) }
    BLK8(8, true)
    if (!isM2) endst[c * 8 + h] = m;     // m1 state at t = ts+CHL
    BLK8(0, true)
    if (isM2) endst[c * 8 + h] = m;      // m2 state at t = ts+CHL
#undef BLK8
}

// waves_per_eu(1): only ~1.56 waves/SIMD exist grid-wide, so removing any
// occupancy-driven register-pressure target costs nothing and lets the
// clustered loads stay register-resident (expect VGPR_Count >= ~56).
__global__ void __launch_bounds__(64) __attribute__((amdgpu_waves_per_eu(1)))
snn_chunks(const float* __restrict__ ws,
           const float* __restrict__ b1g, const float* __restrict__ w2g,
           const float* __restrict__ b2g,
           float* __restrict__ out, float* __restrict__ spec,
           float* __restrict__ endst) {
    __shared__ float lutT[3 * 33];       // padded LUT: lutT[o*33+mask] -> bank (o+mask)
    int lane = threadIdx.x;
    if (lane < 32) {                      // exact: lutT[o*33+mask] = w2[o]@bits(mask)
#pragma clang fp contract(off)
        float b0 = (float)(lane & 1), b1v = (float)((lane >> 1) & 1),
              b2v = (float)((lane >> 2) & 1), b3v = (float)((lane >> 3) & 1),
              b4v = (float)((lane >> 4) & 1);
#pragma unroll
        for (int o = 0; o < NOUT; ++o) {
            float d = w2g[o * NHID + 0] * b0;
            d = d + w2g[o * NHID + 1] * b1v;
            d = d + w2g[o * NHID + 2] * b2v;
            d = d + w2g[o * NHID + 3] * b3v;
            d = d + w2g[o * NHID + 4] * b4v;
            lutT[o * 33 + lane] = d;
        }
    }
    __syncthreads();
    int g = lane >> 3, h = lane & 7;
    bool isM2 = (h >= NHID);
    float bias = isM2 ? b2g[h - NHID] : b1g[h];
    int c = blockIdx.x * GPW + g;
    int gsh = g << 3;                              // ballot >> (group*8)
    const char* lutrow = (const char*)lutT + (isM2 ? ((h - NHID) * 132) : 0);
    const char* dotb = (const char*)(ws + WS_DOT);
    char* outb  = (char*)out;
    char* out2b = (char*)(out + OUTHALF);
    if (blockIdx.x == 0)
        run_chunks<true >(dotb, lutrow, bias, c, h, isM2, gsh, outb, out2b, spec, endst);
    else
        run_chunks<false>(dotb, lutrow, bias, c, h, isM2, gsh, outb, out2b, spec, endst);
}

// ---- exact scalar step (fallback path only) ----
template<bool STORE>
__device__ __forceinline__ void lif_step(int t, const float* __restrict__ dot,
                                         float m1[NHID], float m2[NOUT],
                                         const float B1[NHID],
                                         const float W2[NOUT][NHID],
                                         const float B2[NOUT],
                                         float* __restrict__ out) {
#pragma clang fp contract(off)
    int r = t & (ROWN - 1);
    const float4 lo = *reinterpret_cast<const float4*>(dot + r * 8);
    const float d4 = dot[r * 8 + 4];
    float dv[NHID] = { lo.x, lo.y, lo.z, lo.w, d4 };
    float s1f[NHID];
#pragma unroll
    for (int h = 0; h < NHID; ++h) {
        float u = 0.9f * m1[h];
        u = u + dv[h];
        u = u + B1[h];
        float s = (u > 1.0f) ? 1.0f : 0.0f;
        m1[h] = u - s;
        s1f[h] = s;
    }
#pragma unroll
    for (int o = 0; o < NOUT; ++o) {
        float d2 = W2[o][0] * s1f[0];
        d2 = d2 + W2[o][1] * s1f[1];
        d2 = d2 + W2[o][2] * s1f[2];
        d2 = d2 + W2[o][3] * s1f[3];
        d2 = d2 + W2[o][4] * s1f[4];
        float u = 0.9f * m2[o];
        u = u + d2;
        u = u + B2[o];
        float s = (u > 1.0f) ? 1.0f : 0.0f;
        m2[o] = u - s;
        if (STORE) {
            out[t * NOUT + o] = s;
            out[OUTHALF + t * NOUT + o] = s;
        }
    }
}

// Chain verification: chunk c's post-warmup state must equal chunk c-1's end
// state bitwise. All-equal + exact chunk 0 => outputs exact by induction.
__global__ void snn_check(const float* __restrict__ spec,
                          const float* __restrict__ endst,
                          int* __restrict__ flag) {
    int c = blockIdx.x * blockDim.x + threadIdx.x;
    if (c < 1 || c >= NCH) return;
    bool bad = false;
#pragma unroll
    for (int i = 0; i < 8; ++i)
        bad = bad || (spec[c * 8 + i] != endst[(c - 1) * 8 + i]);
    if (bad) atomicOr(flag, 1);
}

// Exact sequential fallback (runs only if speculation failed anywhere).
__global__ void snn_fallback(const float* __restrict__ ws_dot,
                             const float* __restrict__ b1g,
                             const float* __restrict__ w2g,
                             const float* __restrict__ b2g,
                             float* __restrict__ out,
                             const int* __restrict__ flag) {
    if (*flag == 0) return;
    float B1[NHID], W2[NOUT][NHID], B2[NOUT];
#pragma unroll
    for (int h = 0; h < NHID; ++h) B1[h] = b1g[h];
#pragma unroll
    for (int o = 0; o < NOUT; ++o) {
        B2[o] = b2g[o];
#pragma unroll
        for (int h = 0; h < NHID; ++h) W2[o][h] = w2g[o * NHID + h];
    }
    float m1[NHID] = {0,0,0,0,0};
    float m2[NOUT] = {0,0,0};
    for (int t = 0; t < TTOT; ++t)
        lif_step<true>(t, ws_dot, m1, m2, B1, W2, B2, out);
}

extern "C" void kernel_launch(void* const* d_in, const int* in_sizes, int n_in,
                              void* d_out, int out_size, void* d_ws, size_t ws_size,
                              hipStream_t stream) {
    const float* data = (const float*)d_in[0];
    const float* w1   = (const float*)d_in[1];
    const float* b1   = (const float*)d_in[2];
    const float* w2   = (const float*)d_in[3];
    const float* b2   = (const float*)d_in[4];
    float* out = (float*)d_out;
    float* ws  = (float*)d_ws;
    float* spec  = ws + WS_SPEC;
    float* endst = ws + WS_END;
    int*   flag  = (int*)(ws + WS_FLAG);

    hipLaunchKernelGGL(snn_dots,   dim3(ROWN / 256), dim3(256), 0, stream, data, w1, ws);
    hipLaunchKernelGGL(snn_chunks, dim3(NBLK),       dim3(64),  0, stream,
                       ws, b1, w2, b2, out, spec, endst);
    hipLaunchKernelGGL(snn_check,  dim3((NCH + 255) / 256), dim3(256), 0, stream,
                       spec, endst, flag);
    hipLaunchKernelGGL(snn_fallback, dim3(1), dim3(1), 0, stream,
                       ws, b1, w2, b2, out, flag);
}

// Round 5
// 41.006 us; speedup vs baseline: 4.0307x; 1.0022x over previous
//
#include <hip/hip_runtime.h>

// ---- problem constants (fixed by reference) ----
#define ROWN   32768
#define NSTEP  25
#define NIN    36
#define NHID   5
#define NOUT   3
#define TTOT   (NSTEP * ROWN)      // 819200 total LIF steps
#define OUTHALF (TTOT * NOUT)      // 2457600 floats per tuple element

// ---- speculation / parallelization parameters ----
#define CHL    64                  // chunk length (steps) -> 1600 waves
#define WARM   384                 // warmup steps (bitwise-verified)
#define NCH    (TTOT / CHL)        // 12800 chunks
#define GPW    8                   // chunks per wave (8 lanes per chunk)
#define NBLK   (NCH / GPW)         // 1600 blocks of 64 threads
#define EXT    640                 // duplicated rows appended to dot table
                                   // max row touched: 32767 + 471 = 33238 < 33408

// ---- ws layout (float offsets) ----
#define DOTROWS (ROWN + EXT)
#define WS_DOT  0                  // [DOTROWS][8] padded dot products (~1.07 MB)
#define WS_SPEC (DOTROWS * 8)      // [NCH][8] speculative post-warmup states
#define WS_END  (WS_SPEC + NCH*8)  // [NCH][8] chunk end states
#define WS_FLAG (WS_END + NCH*8)   // int flag

// Precompute dot1[r][h] = sum_j w1[h][j]*data[r][j], exact sequential-j order,
// contract off (matches reference fp trajectory bitwise). Rows 0..EXT-1 are
// duplicated at ROWN+r so the scan loop needs no wrap mask.
__global__ void snn_dots(const float* __restrict__ data,
                         const float* __restrict__ w1,
                         float* __restrict__ ws) {
#pragma clang fp contract(off)
    int r = blockIdx.x * blockDim.x + threadIdx.x;
    if (r == 0) ((int*)ws)[WS_FLAG] = 0;
    if (r >= ROWN) return;
    const float4* x4 = reinterpret_cast<const float4*>(data + r * NIN);
    float4 xv[9];
#pragma unroll
    for (int q = 0; q < 9; ++q) xv[q] = x4[q];
    const float* xs = reinterpret_cast<const float*>(xv);
    float acc[NHID] = {0.f, 0.f, 0.f, 0.f, 0.f};
#pragma unroll
    for (int j = 0; j < NIN; ++j) {
        float x = xs[j];
#pragma unroll
        for (int h = 0; h < NHID; ++h) {
            float p = w1[h * NIN + j] * x;
            acc[h] = acc[h] + p;
        }
    }
    float* d = ws + WS_DOT + r * 8;
#pragma unroll
    for (int h = 0; h < NHID; ++h) d[h] = acc[h];
    d[5] = 0.f; d[6] = 0.f; d[7] = 0.f;
    if (r < EXT) {
        float* d2 = ws + WS_DOT + (ROWN + r) * 8;
#pragma unroll
        for (int h = 0; h < NHID; ++h) d2[h] = acc[h];
        d2[5] = 0.f; d2[6] = 0.f; d2[7] = 0.f;
    }
}

// ---- 8-lane-per-chunk speculative scan, FULLY SCALARIZED pipeline ----
// lane = g*8 + h.  h<5: m1 comp h (input = dot[t][h], global, 16-deep prefetch).
//                  h>=5: m2 comp h-5 (input = LUT d2, 8 steps behind m1).
// Unified step: m = (0.9*m + inp) + bias; spike iff m>1; m -= spike.
// NEW vs round 4: dvbuf[16]/d2buf[8]/sbuf[8] arrays are replaced by NAMED
// scalars dv0..dv15 / e0..e7 / s0..s7. Round-0's VGPR_Count=24 proved the
// arrays lived in SCRATCH (32 live floats can't fit 24 VGPRs), making every
// pipeline access an L2-latency load — the ~160cy/step observed. Named SSA
// values force true register allocation. Arithmetic sequence is unchanged.
template<bool GUARD>
__device__ __forceinline__ void run_chunks(
    const char* __restrict__ dotb,      // byte base of dot table
    const char* __restrict__ lutrow,    // this lane's LUT row base (LDS, stride 33)
    float bias, int c, int h, bool isM2, int gsh,
    char* __restrict__ outb, char* __restrict__ out2b,
    float* __restrict__ spec, float* __restrict__ endst)
{
#pragma clang fp contract(off)
    const int ts = c * CHL;
    const int t0 = ts - WARM;                     // <0 only in GUARD block
    float m = 0.0f;
    const int dco = (isM2 ? 4 : h) << 2;          // dot col byte off (m2: dummy, coalesced)
    unsigned offb = ((unsigned)(t0 & (ROWN - 1)) << 5) + (unsigned)dco;

    // prime the 16-deep dot pipeline (named registers)
    float dv0  = *(const float*)(dotb + offb +  0 * 32);
    float dv1  = *(const float*)(dotb + offb +  1 * 32);
    float dv2  = *(const float*)(dotb + offb +  2 * 32);
    float dv3  = *(const float*)(dotb + offb +  3 * 32);
    float dv4  = *(const float*)(dotb + offb +  4 * 32);
    float dv5  = *(const float*)(dotb + offb +  5 * 32);
    float dv6  = *(const float*)(dotb + offb +  6 * 32);
    float dv7  = *(const float*)(dotb + offb +  7 * 32);
    float dv8  = *(const float*)(dotb + offb +  8 * 32);
    float dv9  = *(const float*)(dotb + offb +  9 * 32);
    float dv10 = *(const float*)(dotb + offb + 10 * 32);
    float dv11 = *(const float*)(dotb + offb + 11 * 32);
    float dv12 = *(const float*)(dotb + offb + 12 * 32);
    float dv13 = *(const float*)(dotb + offb + 13 * 32);
    float dv14 = *(const float*)(dotb + offb + 14 * 32);
    float dv15 = *(const float*)(dotb + offb + 15 * 32);
    offb += 16 * 32;
    float e0 = 0.f, e1 = 0.f, e2 = 0.f, e3 = 0.f,
          e4 = 0.f, e5 = 0.f, e6 = 0.f, e7 = 0.f;
    float s0 = 0.f, s1 = 0.f, s2 = 0.f, s3 = 0.f,
          s4 = 0.f, s5 = 0.f, s6 = 0.f, s7 = 0.f;
    int tg = t0 - (isM2 ? 8 : 0);                 // logical clock (GUARD only)
    unsigned obb = (unsigned)ts * 12u + (unsigned)((isM2 ? (h - NHID) : 0) << 2);

// one LIF step: consume DV (m1) / EV (m2), refresh EV from LUT, record SV.
#define LSTEP(DV, EV, SV, STORE)                                             \
  {                                                                          \
    float inp = isM2 ? EV : DV;                                              \
    float u = 0.9f * m;                                                      \
    u = u + inp;                                                             \
    u = u + bias;                                                            \
    bool sp = u > 1.0f;                                                      \
    unsigned long long bal = __ballot(sp);                                   \
    float um1 = u - 1.0f;                                                    \
    m = sp ? um1 : u;                                                        \
    if (GUARD) { if (tg < 0) m = 0.0f; ++tg; }                               \
    unsigned a = (unsigned)((bal << 2) >> gsh) & 124u;                       \
    EV = *(const float*)(lutrow + a);                                        \
    if (STORE) SV = sp ? 1.0f : 0.0f;                                        \
  }

#define RELOAD(DV, K) DV = *(const float*)(dotb + offb + (K) * 32);

#define STOREOUT                                                             \
    if (isM2) {                                                              \
        *(float*)(outb + obb + 0*12) = s0; *(float*)(out2b + obb + 0*12) = s0; \
        *(float*)(outb + obb + 1*12) = s1; *(float*)(out2b + obb + 1*12) = s1; \
        *(float*)(outb + obb + 2*12) = s2; *(float*)(out2b + obb + 2*12) = s2; \
        *(float*)(outb + obb + 3*12) = s3; *(float*)(out2b + obb + 3*12) = s3; \
        *(float*)(outb + obb + 4*12) = s4; *(float*)(out2b + obb + 4*12) = s4; \
        *(float*)(outb + obb + 5*12) = s5; *(float*)(out2b + obb + 5*12) = s5; \
        *(float*)(outb + obb + 6*12) = s6; *(float*)(out2b + obb + 6*12) = s6; \
        *(float*)(outb + obb + 7*12) = s7; *(float*)(out2b + obb + 7*12) = s7; \
    }                                                                        \
    obb += 96u;

// 8-step block, half 0 (consumes/reloads dv0..dv7)
#define BLK0(STORE)                                                          \
  {                                                                          \
    LSTEP(dv0, e0, s0, STORE) LSTEP(dv1, e1, s1, STORE)                      \
    LSTEP(dv2, e2, s2, STORE) LSTEP(dv3, e3, s3, STORE)                      \
    LSTEP(dv4, e4, s4, STORE) LSTEP(dv5, e5, s5, STORE)                      \
    LSTEP(dv6, e6, s6, STORE) LSTEP(dv7, e7, s7, STORE)                      \
    RELOAD(dv0, 0) RELOAD(dv1, 1) RELOAD(dv2, 2) RELOAD(dv3, 3)              \
    RELOAD(dv4, 4) RELOAD(dv5, 5) RELOAD(dv6, 6) RELOAD(dv7, 7)              \
    offb += 256u;                                                            \
    if (STORE) { STOREOUT }                                                  \
    __builtin_amdgcn_sched_barrier(0);                                       \
  }

// 8-step block, half 8 (consumes/reloads dv8..dv15)
#define BLK8M(STORE)                                                         \
  {                                                                          \
    LSTEP(dv8,  e0, s0, STORE) LSTEP(dv9,  e1, s1, STORE)                    \
    LSTEP(dv10, e2, s2, STORE) LSTEP(dv11, e3, s3, STORE)                    \
    LSTEP(dv12, e4, s4, STORE) LSTEP(dv13, e5, s5, STORE)                    \
    LSTEP(dv14, e6, s6, STORE) LSTEP(dv15, e7, s7, STORE)                    \
    RELOAD(dv8,  0) RELOAD(dv9,  1) RELOAD(dv10, 2) RELOAD(dv11, 3)          \
    RELOAD(dv12, 4) RELOAD(dv13, 5) RELOAD(dv14, 6) RELOAD(dv15, 7)          \
    offb += 256u;                                                            \
    if (STORE) { STOREOUT }                                                  \
    __builtin_amdgcn_sched_barrier(0);                                       \
  }

    // warmup: 48 blocks = 384 steps (halves alternate 0,8)
    for (int n = 0; n < 24; ++n) { BLK0(false) BLK8M(false) }
    if (!isM2) spec[c * 8 + h] = m;      // m1 state at t = ts
    BLK0(false)                           // m2 finishes warmup
    if (isM2) spec[c * 8 + h] = m;       // m2 state at t = ts
    // store region: 8 blocks = 64 m2-steps (halves 8,0,8,0,8,0,8,0)
    for (int n = 0; n < 3; ++n) { BLK8M(true) BLK0(true) }
    BLK8M(true)
    if (!isM2) endst[c * 8 + h] = m;     // m1 state at t = ts+CHL
    BLK0(true)
    if (isM2) endst[c * 8 + h] = m;      // m2 state at t = ts+CHL
#undef BLK0
#undef BLK8M
#undef STOREOUT
#undef RELOAD
#undef LSTEP
}

// waves_per_eu(1): only ~1.56 waves/SIMD exist grid-wide, so removing the
// occupancy-driven register-pressure target costs nothing.
__global__ void __launch_bounds__(64) __attribute__((amdgpu_waves_per_eu(1)))
snn_chunks(const float* __restrict__ ws,
           const float* __restrict__ b1g, const float* __restrict__ w2g,
           const float* __restrict__ b2g,
           float* __restrict__ out, float* __restrict__ spec,
           float* __restrict__ endst) {
    __shared__ float lutT[3 * 33];       // padded LUT: lutT[o*33+mask] -> bank (o+mask)
    int lane = threadIdx.x;
    if (lane < 32) {                      // exact: lutT[o*33+mask] = w2[o]@bits(mask)
#pragma clang fp contract(off)
        float b0 = (float)(lane & 1), b1v = (float)((lane >> 1) & 1),
              b2v = (float)((lane >> 2) & 1), b3v = (float)((lane >> 3) & 1),
              b4v = (float)((lane >> 4) & 1);
#pragma unroll
        for (int o = 0; o < NOUT; ++o) {
            float d = w2g[o * NHID + 0] * b0;
            d = d + w2g[o * NHID + 1] * b1v;
            d = d + w2g[o * NHID + 2] * b2v;
            d = d + w2g[o * NHID + 3] * b3v;
            d = d + w2g[o * NHID + 4] * b4v;
            lutT[o * 33 + lane] = d;
        }
    }
    __syncthreads();
    int g = lane >> 3, h = lane & 7;
    bool isM2 = (h >= NHID);
    float bias = isM2 ? b2g[h - NHID] : b1g[h];
    int c = blockIdx.x * GPW + g;
    int gsh = g << 3;                              // ballot >> (group*8)
    const char* lutrow = (const char*)lutT + (isM2 ? ((h - NHID) * 132) : 0);
    const char* dotb = (const char*)(ws + WS_DOT);
    char* outb  = (char*)out;
    char* out2b = (char*)(out + OUTHALF);
    if (blockIdx.x == 0)
        run_chunks<true >(dotb, lutrow, bias, c, h, isM2, gsh, outb, out2b, spec, endst);
    else
        run_chunks<false>(dotb, lutrow, bias, c, h, isM2, gsh, outb, out2b, spec, endst);
}

// ---- exact scalar step (fallback path only) ----
template<bool STORE>
__device__ __forceinline__ void lif_step(int t, const float* __restrict__ dot,
                                         float m1[NHID], float m2[NOUT],
                                         const float B1[NHID],
                                         const float W2[NOUT][NHID],
                                         const float B2[NOUT],
                                         float* __restrict__ out) {
#pragma clang fp contract(off)
    int r = t & (ROWN - 1);
    const float4 lo = *reinterpret_cast<const float4*>(dot + r * 8);
    const float d4 = dot[r * 8 + 4];
    float dv[NHID] = { lo.x, lo.y, lo.z, lo.w, d4 };
    float s1f[NHID];
#pragma unroll
    for (int h = 0; h < NHID; ++h) {
        float u = 0.9f * m1[h];
        u = u + dv[h];
        u = u + B1[h];
        float s = (u > 1.0f) ? 1.0f : 0.0f;
        m1[h] = u - s;
        s1f[h] = s;
    }
#pragma unroll
    for (int o = 0; o < NOUT; ++o) {
        float d2 = W2[o][0] * s1f[0];
        d2 = d2 + W2[o][1] * s1f[1];
        d2 = d2 + W2[o][2] * s1f[2];
        d2 = d2 + W2[o][3] * s1f[3];
        d2 = d2 + W2[o][4] * s1f[4];
        float u = 0.9f * m2[o];
        u = u + d2;
        u = u + B2[o];
        float s = (u > 1.0f) ? 1.0f : 0.0f;
        m2[o] = u - s;
        if (STORE) {
            out[t * NOUT + o] = s;
            out[OUTHALF + t * NOUT + o] = s;
        }
    }
}

// Chain verification: chunk c's post-warmup state must equal chunk c-1's end
// state bitwise. All-equal + exact chunk 0 => outputs exact by induction.
__global__ void snn_check(const float* __restrict__ spec,
                          const float* __restrict__ endst,
                          int* __restrict__ flag) {
    int c = blockIdx.x * blockDim.x + threadIdx.x;
    if (c < 1 || c >= NCH) return;
    bool bad = false;
#pragma unroll
    for (int i = 0; i < 8; ++i)
        bad = bad || (spec[c * 8 + i] != endst[(c - 1) * 8 + i]);
    if (bad) atomicOr(flag, 1);
}

// Exact sequential fallback (runs only if speculation failed anywhere).
__global__ void snn_fallback(const float* __restrict__ ws_dot,
                             const float* __restrict__ b1g,
                             const float* __restrict__ w2g,
                             const float* __restrict__ b2g,
                             float* __restrict__ out,
                             const int* __restrict__ flag) {
    if (*flag == 0) return;
    float B1[NHID], W2[NOUT][NHID], B2[NOUT];
#pragma unroll
    for (int h = 0; h < NHID; ++h) B1[h] = b1g[h];
#pragma unroll
    for (int o = 0; o < NOUT; ++o) {
        B2[o] = b2g[o];
#pragma unroll
        for (int h = 0; h < NHID; ++h) W2[o][h] = w2g[o * NHID + h];
    }
    float m1[NHID] = {0,0,0,0,0};
    float m2[NOUT] = {0,0,0};
    for (int t = 0; t < TTOT; ++t)
        lif_step<true>(t, ws_dot, m1, m2, B1, W2, B2, out);
}

extern "C" void kernel_launch(void* const* d_in, const int* in_sizes, int n_in,
                              void* d_out, int out_size, void* d_ws, size_t ws_size,
                              hipStream_t stream) {
    const float* data = (const float*)d_in[0];
    const float* w1   = (const float*)d_in[1];
    const float* b1   = (const float*)d_in[2];
    const float* w2   = (const float*)d_in[3];
    const float* b2   = (const float*)d_in[4];
    float* out = (float*)d_out;
    float* ws  = (float*)d_ws;
    float* spec  = ws + WS_SPEC;
    float* endst = ws + WS_END;
    int*   flag  = (int*)(ws + WS_FLAG);

    hipLaunchKernelGGL(snn_dots,   dim3(ROWN / 256), dim3(256), 0, stream, data, w1, ws);
    hipLaunchKernelGGL(snn_chunks, dim3(NBLK),       dim3(64),  0, stream,
                       ws, b1, w2, b2, out, spec, endst);
    hipLaunchKernelGGL(snn_check,  dim3((NCH + 255) / 256), dim3(256), 0, stream,
                       spec, endst, flag);
    hipLaunchKernelGGL(snn_fallback, dim3(1), dim3(1), 0, stream,
                       ws, b1, w2, b2, out, flag);
}